// Round 11
// baseline (450.361 us; speedup 1.0000x reference)
//
#include <hip/hip_runtime.h>

typedef unsigned short u16;
typedef __bf16 bf16_t;
typedef bf16_t bf16x8 __attribute__((ext_vector_type(8)));
typedef float f32x4 __attribute__((ext_vector_type(4)));

#define T_TOK 8192
#define DIM   1024
#define FF    512
#define NE    16
#define RBASE_SHARED (2 * T_TOK)     // shared group rowbase = 16384
#define NROWS (RBASE_SHARED + T_TOK) // 24576 total row-slots
#define MAXTILES 256
#define NSEG 512                     // 16 tokens per segment

__device__ __forceinline__ u16 f2bf(float f) {
  union { float f; unsigned u; } v; v.f = f;
  unsigned r = v.u + 0x7FFFu + ((v.u >> 16) & 1u);
  return (u16)(r >> 16);
}
__device__ __forceinline__ float bf2f(u16 h) {
  union { unsigned u; float f; } v; v.u = ((unsigned)h) << 16; return v.f;
}
__device__ __forceinline__ int clampi(int v, int lo, int hi) {
  return v < lo ? lo : (v > hi ? hi : v);
}

// async global->LDS, 16B per lane; LDS dest = wave-uniform base + lane*16
#define GLL16(g, l) __builtin_amdgcn_global_load_lds( \
    (const __attribute__((address_space(1))) void*)(g), \
    (__attribute__((address_space(3))) void*)(l), 16, 0, 0)

// fused waitcnt+barrier: single volatile asm with memory clobber = compile-time
// fence; no memory op can cross, and waitcnt/barrier are adjacent in the stream.
#define WAIT_VM_BARRIER(n) asm volatile("s_waitcnt vmcnt(" #n ")\n\ts_barrier" ::: "memory")
#define WAIT_LGKM0()       asm volatile("s_waitcnt lgkmcnt(0)" ::: "memory")

#define SW4  131072    // each shared weight: 512*1024/4
#define EW4  2097152   // each expert weight set: 16*512*1024/4
#define TOTW4 (3 * SW4 + 3 * EW4)   // 6684672; /256 = 26112 blocks

// ---------------- fused router + weight-convert kernel ----------------
// Blocks [0, NSEG): router (also emits bf16 x). Blocks [NSEG, ...): fp32->bf16
// weight conversion. Independent work fused into ONE launch so the BW-bound
// convert overlaps the router instead of serializing after scatter.
__global__ __launch_bounds__(256) void router_cvt_kernel(
    const float* __restrict__ x, const float* __restrict__ gw,
    const float* __restrict__ ebias, float* __restrict__ probs,
    int* __restrict__ topi, float* __restrict__ topw, int* __restrict__ cnt_seg,
    u16* __restrict__ xb,
    const float* __restrict__ sw1, const float* __restrict__ sw2,
    const float* __restrict__ sw3, const float* __restrict__ ew1,
    const float* __restrict__ ew2, const float* __restrict__ ew3,
    u16* __restrict__ sw1b, u16* __restrict__ sw2b, u16* __restrict__ sw3b,
    u16* __restrict__ ew1b, u16* __restrict__ ew2b, u16* __restrict__ ew3b) {
  int tid = threadIdx.x;
  if (blockIdx.x >= NSEG) {
    // ---- convert path ----
    int i = (blockIdx.x - NSEG) * 256 + tid;
    const float* s; u16* dst; int j;
    if (i < SW4)                      { s = sw1; dst = sw1b; j = i; }
    else if (i < 2 * SW4)             { s = sw2; dst = sw2b; j = i - SW4; }
    else if (i < 3 * SW4)             { s = sw3; dst = sw3b; j = i - 2 * SW4; }
    else if (i < 3 * SW4 + EW4)       { s = ew1; dst = ew1b; j = i - 3 * SW4; }
    else if (i < 3 * SW4 + 2 * EW4)   { s = ew2; dst = ew2b; j = i - (3 * SW4 + EW4); }
    else if (i < TOTW4)               { s = ew3; dst = ew3b; j = i - (3 * SW4 + 2 * EW4); }
    else return;
    float4 v = reinterpret_cast<const float4*>(s)[j];
    ushort4 o;
    o.x = f2bf(v.x); o.y = f2bf(v.y); o.z = f2bf(v.z); o.w = f2bf(v.w);
    reinterpret_cast<ushort4*>(dst)[j] = o;
    return;
  }
  // ---- router path ----
  __shared__ int hist[16];
  int lane = tid & 63, w = tid >> 6;
  if (tid < 16) hist[tid] = 0;
  __syncthreads();
  const float4* gv = reinterpret_cast<const float4*>(gw);
  for (int it = 0; it < 2; ++it) {
    int t0 = blockIdx.x * 16 + (w + 4 * it) * 2;
    const float4* x0 = reinterpret_cast<const float4*>(x + (size_t)t0 * DIM);
    const float4* x1 = reinterpret_cast<const float4*>(x + (size_t)(t0 + 1) * DIM);
    float4 xa[4], xc[4];
#pragma unroll
    for (int j = 0; j < 4; ++j) { xa[j] = x0[j * 64 + lane]; xc[j] = x1[j * 64 + lane]; }
    u16* xr0 = xb + (size_t)t0 * DIM;
    u16* xr1 = xb + (size_t)(t0 + 1) * DIM;
#pragma unroll
    for (int j = 0; j < 4; ++j) {
      ushort4 o0, o1;
      o0.x = f2bf(xa[j].x); o0.y = f2bf(xa[j].y); o0.z = f2bf(xa[j].z); o0.w = f2bf(xa[j].w);
      o1.x = f2bf(xc[j].x); o1.y = f2bf(xc[j].y); o1.z = f2bf(xc[j].z); o1.w = f2bf(xc[j].w);
      reinterpret_cast<ushort4*>(xr0)[j * 64 + lane] = o0;
      reinterpret_cast<ushort4*>(xr1)[j * 64 + lane] = o1;
    }
    float p0[16], p1[16];
#pragma unroll
    for (int e = 0; e < NE; ++e) {
      float s0 = 0.f, s1 = 0.f;
#pragma unroll
      for (int j = 0; j < 4; ++j) {
        float4 g = gv[e * 256 + j * 64 + lane];
        s0 += xa[j].x * g.x + xa[j].y * g.y + xa[j].z * g.z + xa[j].w * g.w;
        s1 += xc[j].x * g.x + xc[j].y * g.y + xc[j].z * g.z + xc[j].w * g.w;
      }
#pragma unroll
      for (int d = 1; d < 64; d <<= 1) { s0 += __shfl_xor(s0, d); s1 += __shfl_xor(s1, d); }
      float b = ebias[e];
      p0[e] = s0 + b; p1[e] = s1 + b;
    }
    float m0 = p0[0], m1 = p1[0];
#pragma unroll
    for (int e = 1; e < NE; ++e) { m0 = fmaxf(m0, p0[e]); m1 = fmaxf(m1, p1[e]); }
    float sum0 = 0.f, sum1 = 0.f;
#pragma unroll
    for (int e = 0; e < NE; ++e) {
      p0[e] = __expf(p0[e] - m0); sum0 += p0[e];
      p1[e] = __expf(p1[e] - m1); sum1 += p1[e];
    }
    float inv0 = 1.f / sum0, inv1 = 1.f / sum1;
#pragma unroll
    for (int e = 0; e < NE; ++e) { p0[e] *= inv0; p1[e] *= inv1; }
    if (lane == 0) {
#pragma unroll
      for (int j = 0; j < 4; ++j)
        reinterpret_cast<float4*>(probs + (size_t)t0 * NE)[j] =
            make_float4(p0[4 * j], p0[4 * j + 1], p0[4 * j + 2], p0[4 * j + 3]);
      float b1 = -1.f, b2 = -1.f; int i1 = 0, i2 = 0;
#pragma unroll
      for (int e = 0; e < NE; ++e) {
        float pe = p0[e];
        if (pe > b1) { b2 = b1; i2 = i1; b1 = pe; i1 = e; }
        else if (pe > b2) { b2 = pe; i2 = e; }
      }
      float ws = b1 + b2;
      reinterpret_cast<int2*>(topi)[t0] = make_int2(i1, i2);
      reinterpret_cast<float2*>(topw)[t0] = make_float2(b1 / ws, b2 / ws);
      atomicAdd(&hist[i1], 1); atomicAdd(&hist[i2], 1);
    }
    if (lane == 1) {
      int t1 = t0 + 1;
#pragma unroll
      for (int j = 0; j < 4; ++j)
        reinterpret_cast<float4*>(probs + (size_t)t1 * NE)[j] =
            make_float4(p1[4 * j], p1[4 * j + 1], p1[4 * j + 2], p1[4 * j + 3]);
      float b1 = -1.f, b2 = -1.f; int i1 = 0, i2 = 0;
#pragma unroll
      for (int e = 0; e < NE; ++e) {
        float pe = p1[e];
        if (pe > b1) { b2 = b1; i2 = i1; b1 = pe; i1 = e; }
        else if (pe > b2) { b2 = pe; i2 = e; }
      }
      float ws = b1 + b2;
      reinterpret_cast<int2*>(topi)[t1] = make_int2(i1, i2);
      reinterpret_cast<float2*>(topw)[t1] = make_float2(b1 / ws, b2 / ws);
      atomicAdd(&hist[i1], 1); atomicAdd(&hist[i2], 1);
    }
  }
  __syncthreads();
  if (tid < 16) cnt_seg[blockIdx.x * 16 + tid] = hist[tid];
}

// ---------------- scan: parallel prefix over segments, tile table ----------------
// tab is XCD-CHUNKED: tab[c*32+slot] = tiles for XCD chunk c. Routed experts
// assigned whole to least-loaded chunk; shared tiles round-robin 8/chunk.
__global__ __launch_bounds__(256) void scan_kernel(
    const int* __restrict__ cnt_seg, int* __restrict__ cnt, int* __restrict__ offs,
    int* __restrict__ seg_base, int2* __restrict__ tab) {
  __shared__ int chunk_sum[16][16];   // [chunk][e], chunk = 32 segs
  __shared__ int chunk_base[16][16];
  __shared__ int tot[16], off_s[17];
  int tid = threadIdx.x;
  int e = tid & 15, c = tid >> 4;
  int s0 = 0;
  for (int s = 0; s < 32; ++s) s0 += cnt_seg[(c * 32 + s) * 16 + e];
  chunk_sum[c][e] = s0;
  __syncthreads();
  if (tid < 16) {
    int r = 0;
    for (int c2 = 0; c2 < 16; ++c2) { chunk_base[c2][tid] = r; r += chunk_sum[c2][tid]; }
    tot[tid] = r;
  }
  __syncthreads();
  if (tid == 0) {
    int a = 0;
    for (int i = 0; i < 16; ++i) { off_s[i] = a; offs[i] = a; cnt[i] = tot[i]; a += tot[i]; }
    off_s[16] = RBASE_SHARED; offs[16] = RBASE_SHARED;
    for (int i = 0; i < MAXTILES; ++i) tab[i] = make_int2(-1, 0);
    int loadc[8]  = {0, 0, 0, 0, 0, 0, 0, 0};
    int cursor[8] = {0, 0, 0, 0, 0, 0, 0, 0};
    for (int g = 0; g < 16; ++g) {                // routed experts
      int nt = (tot[g] + 127) >> 7;
      if (nt == 0) continue;
      int best = 0;
      for (int c2 = 1; c2 < 8; ++c2) if (loadc[c2] < loadc[best]) best = c2;
      loadc[best] += nt;
      int c2 = best;
      for (int ti = 0; ti < nt; ++ti) {
        while (cursor[c2] >= 32) c2 = (c2 + 1) & 7;   // spill (rare), keeps all tiles
        tab[c2 * 32 + cursor[c2]] = make_int2(g, ti * 128);
        cursor[c2]++;
      }
    }
    for (int ti = 0; ti < 64; ++ti) {             // shared: 8 tiles per chunk
      int c2 = ti & 7;
      while (cursor[c2] >= 32) c2 = (c2 + 1) & 7;
      tab[c2 * 32 + cursor[c2]] = make_int2(16, ti * 128);
      cursor[c2]++;
    }
  }
  __syncthreads();
  int r = off_s[e] + chunk_base[c][e];
  for (int s = 0; s < 32; ++s) {
    int seg = c * 32 + s;
    seg_base[seg * 16 + e] = r;
    r += cnt_seg[seg * 16 + e];
  }
}

// ---------------- scatter: deterministic ranks, NO atomics ----------------
__global__ __launch_bounds__(64) void scatter_kernel(
    const int* __restrict__ topi, const float* __restrict__ topw,
    const int* __restrict__ seg_base,
    int* __restrict__ idx, float* __restrict__ cwl, int* __restrict__ slotmap) {
  __shared__ int ti[16][2]; __shared__ float tw[16][2]; __shared__ int base[16];
  int b = blockIdx.x;            // 512 segments
  int tid = threadIdx.x;         // 64
  if (tid < 16) {
    int t = b * 16 + tid;
    int2 pp = reinterpret_cast<const int2*>(topi)[t];
    ti[tid][0] = clampi(pp.x, 0, 15); ti[tid][1] = clampi(pp.y, 0, 15);
    float2 ww = reinterpret_cast<const float2*>(topw)[t];
    tw[tid][0] = ww.x; tw[tid][1] = ww.y;
    base[tid] = seg_base[b * 16 + tid];
  }
  __syncthreads();
  if (tid < 32) {
    int l = tid >> 1, s = tid & 1;
    int t = b * 16 + l;
    int e = ti[l][s];
    int rank = 0;
    for (int t2 = 0; t2 < 16; ++t2) {
      if (ti[t2][0] == e && (t2 < l || (t2 == l && 0 < s))) ++rank;
      if (ti[t2][1] == e && (t2 < l)) ++rank;
    }
    int slot = clampi(base[e] + rank, 0, NROWS - 1);
    idx[slot] = t; cwl[slot] = tw[l][s]; slotmap[t * 3 + s] = slot;
  } else if (tid < 48) {
    int l = tid - 32;
    int t = b * 16 + l;
    int sh = RBASE_SHARED + t;
    idx[sh] = t; cwl[sh] = 1.0f; slotmap[t * 3 + 2] = sh;
  }
}

// ---------------- grouped GEMM1: G = silu(A@W1^T) * (A@W3^T), bf16 ----------------
// Round-9 structure (best verified): non-persistent 1024 blocks, ny-fastest
// decode, 3-buffer depth-2 prefetch, single barrier per K-step, vmcnt(6).
__global__ __launch_bounds__(256, 2) void gemm_silu_kernel(
    const u16* __restrict__ A, const u16* __restrict__ sw1b, const u16* __restrict__ sw3b,
    const u16* __restrict__ ew1b, const u16* __restrict__ ew3b, u16* __restrict__ G,
    const int2* __restrict__ tab, const int* __restrict__ offs,
    const int* __restrict__ cnt, const int* __restrict__ gidx) {
  const int K = DIM;
  int orig = blockIdx.x;                  // 1024 blocks, 1-D grid
  int xcd = orig & 7;
  int u = orig >> 3;                      // [0,128)
  int tslot = u >> 2, ny = u & 3;         // ny fastest -> CU = (4*tslot+ny)%32
  int tileid = xcd * 32 + tslot;
  int2 te = tab[tileid];
  int e = te.x;
  if (e < 0) return;                      // block-uniform exit (before barriers)
  e = clampi(e, 0, NE);
  int m0 = te.y;
  int M = (e == NE) ? T_TOK : cnt[e];
  M = clampi(M, 1, T_TOK);
  int rowbase = clampi(offs[e], 0, NROWS - 1);
  const u16* B1 = (e == NE) ? sw1b : ew1b + (size_t)e * FF * K;
  const u16* B3 = (e == NE) ? sw3b : ew3b + (size_t)e * FF * K;
  int n0 = ny * 128;

  __shared__ u16 As[3 * 4096], B1s[3 * 4096], B3s[3 * 4096];   // 72 KB

  int tid = threadIdx.x;
  int lane = tid & 63, wv = tid >> 6;
  int srow = tid >> 2, sg = tid & 3;
  int sk0 = (sg ^ ((srow >> 1) & 3)) * 8;
  int sk1 = (sg ^ (((srow + 64) >> 1) & 3)) * 8;
  int r0 = min(m0 + srow, M - 1);
  int r1 = min(m0 + srow + 64, M - 1);
  int ga0 = clampi(gidx[clampi(rowbase + r0, 0, NROWS - 1)], 0, T_TOK - 1);
  int ga1 = clampi(gidx[clampi(rowbase + r1, 0, NROWS - 1)], 0, T_TOK - 1);
  const u16* Ap0 = A + (size_t)ga0 * K + sk0;
  const u16* Ap1 = A + (size_t)ga1 * K + sk1;
  const u16* B1p0 = B1 + (size_t)(n0 + srow) * K + sk0;
  const u16* B1p1 = B1 + (size_t)(n0 + srow + 64) * K + sk1;
  const u16* B3p0 = B3 + (size_t)(n0 + srow) * K + sk0;
  const u16* B3p1 = B3 + (size_t)(n0 + srow + 64) * K + sk1;
  int st0 = wv * 512, st1 = 2048 + wv * 512;   // per-wave staging dests (u16 units)

  int ln15 = lane & 15, qd = lane >> 4;
  int qsw = (qd ^ ((ln15 >> 1) & 3)) * 8;
  int wm = (wv >> 1) * 64, wn = (wv & 1) * 64;
  int aoff = (wm + ln15) * 32 + qsw;
  int boff = (wn + ln15) * 32 + qsw;

  f32x4 acc1[4][4] = {};
  f32x4 acc3[4][4] = {};

  // prologue: stage tiles 0,1 (12 loads in flight)
#pragma unroll
  for (int b = 0; b < 2; ++b) {
    const int bb = b * 4096, kb = b * 32;
    GLL16(Ap0 + kb, As + bb + st0);      GLL16(Ap1 + kb, As + bb + st1);
    GLL16(B1p0 + kb, B1s + bb + st0);    GLL16(B1p1 + kb, B1s + bb + st1);
    GLL16(B3p0 + kb, B3s + bb + st0);    GLL16(B3p1 + kb, B3s + bb + st1);
  }

#pragma unroll
  for (int t = 0; t < 30; ++t) {     // staging iterations, fully unrolled
    const int cur = (t % 3) * 4096;
    WAIT_VM_BARRIER(6);              // tile t landed; t+1 in flight; buf (t+2)%3 free
    const int nxt = ((t + 2) % 3) * 4096;
    const int kt = (t + 2) * 32;     // stage tile t+2 (earliest issue, imm offsets)
    GLL16(Ap0 + kt, As + nxt + st0);     GLL16(Ap1 + kt, As + nxt + st1);
    GLL16(B1p0 + kt, B1s + nxt + st0);   GLL16(B1p1 + kt, B1s + nxt + st1);
    GLL16(B3p0 + kt, B3s + nxt + st0);   GLL16(B3p1 + kt, B3s + nxt + st1);
    bf16x8 af[4], bx[4];
#pragma unroll
    for (int i = 0; i < 4; ++i) {
      af[i] = *reinterpret_cast<const bf16x8*>(&As[cur + aoff + i * 512]);
      bx[i] = *reinterpret_cast<const bf16x8*>(&B1s[cur + boff + i * 512]);
    }
    WAIT_LGKM0();
    __builtin_amdgcn_sched_barrier(0);
    __builtin_amdgcn_s_setprio(1);
#pragma unroll
    for (int i = 0; i < 4; ++i)
#pragma unroll
      for (int j = 0; j < 4; ++j)
        acc1[i][j] = __builtin_amdgcn_mfma_f32_16x16x32_bf16(af[i], bx[j], acc1[i][j], 0, 0, 0);
    __builtin_amdgcn_s_setprio(0);
    __builtin_amdgcn_sched_barrier(0);   // keep B3 reads AFTER acc1 cluster (frag reg reuse)
#pragma unroll
    for (int i = 0; i < 4; ++i)
      bx[i] = *reinterpret_cast<const bf16x8*>(&B3s[cur + boff + i * 512]);
    WAIT_LGKM0();
    __builtin_amdgcn_sched_barrier(0);
    __builtin_amdgcn_s_setprio(1);
#pragma unroll
    for (int i = 0; i < 4; ++i)
#pragma unroll
      for (int j = 0; j < 4; ++j)
        acc3[i][j] = __builtin_amdgcn_mfma_f32_16x16x32_bf16(af[i], bx[j], acc3[i][j], 0, 0, 0);
    __builtin_amdgcn_s_setprio(0);
  }
  // tail peels: t = 30 (vmcnt 6: tile 31 may still fly), t = 31 (vmcnt 0)
#pragma unroll
  for (int pt = 30; pt < 32; ++pt) {
    const int cur = (pt % 3) * 4096;
    if (pt == 30) { WAIT_VM_BARRIER(6); }
    else          { WAIT_VM_BARRIER(0); }
    bf16x8 af[4], bx[4];
#pragma unroll
    for (int i = 0; i < 4; ++i) {
      af[i] = *reinterpret_cast<const bf16x8*>(&As[cur + aoff + i * 512]);
      bx[i] = *reinterpret_cast<const bf16x8*>(&B1s[cur + boff + i * 512]);
    }
    WAIT_LGKM0();
    __builtin_amdgcn_sched_barrier(0);
    __builtin_amdgcn_s_setprio(1);
#pragma unroll
    for (int i = 0; i < 4; ++i)
#pragma unroll
      for (int j = 0; j < 4; ++j)
        acc1[i][j] = __builtin_amdgcn_mfma_f32_16x16x32_bf16(af[i], bx[j], acc1[i][j], 0, 0, 0);
    __builtin_amdgcn_s_setprio(0);
    __builtin_amdgcn_sched_barrier(0);
#pragma unroll
    for (int i = 0; i < 4; ++i)
      bx[i] = *reinterpret_cast<const bf16x8*>(&B3s[cur + boff + i * 512]);
    WAIT_LGKM0();
    __builtin_amdgcn_sched_barrier(0);
    __builtin_amdgcn_s_setprio(1);
#pragma unroll
    for (int i = 0; i < 4; ++i)
#pragma unroll
      for (int j = 0; j < 4; ++j)
        acc3[i][j] = __builtin_amdgcn_mfma_f32_16x16x32_bf16(af[i], bx[j], acc3[i][j], 0, 0, 0);
    __builtin_amdgcn_s_setprio(0);
  }

  int mrem = M - m0;
#pragma unroll
  for (int i = 0; i < 4; ++i)
#pragma unroll
    for (int r2 = 0; r2 < 4; ++r2) {
      int ml = wm + i * 16 + qd * 4 + r2;
      if (ml < mrem) {
        size_t orow = (size_t)clampi(rowbase + m0 + ml, 0, NROWS - 1);
#pragma unroll
        for (int j = 0; j < 4; ++j) {
          float z1 = acc1[i][j][r2], z3 = acc3[i][j][r2];
          float g = z1 / (1.f + __expf(-z1)) * z3;
          G[orow * FF + n0 + wn + j * 16 + ln15] = f2bf(g);
        }
      }
    }
}

// ---------------- grouped GEMM2: O[slot] = cw * (G @ W2^T), bf16 ----------------
// Round-9 structure: 2048 blocks, ny-fastest decode, depth-2, single barrier.
__global__ __launch_bounds__(256, 2) void gemm_out_kernel(
    const u16* __restrict__ Gb, const u16* __restrict__ sw2b, const u16* __restrict__ ew2b,
    u16* __restrict__ O, const int2* __restrict__ tab, const int* __restrict__ offs,
    const int* __restrict__ cnt, const float* __restrict__ cwl) {
  const int K = FF;
  int orig = blockIdx.x;                  // 2048 blocks, 1-D grid
  int xcd = orig & 7;
  int u = orig >> 3;                      // [0,256)
  int tslot = u >> 3, ny = u & 7;         // ny fastest -> CU = (8*tslot+ny)%32
  int tileid = xcd * 32 + tslot;
  int2 te = tab[tileid];
  int e = te.x;
  if (e < 0) return;
  e = clampi(e, 0, NE);
  int m0 = te.y;
  int M = (e == NE) ? T_TOK : cnt[e];
  M = clampi(M, 1, T_TOK);
  int rowbase = clampi(offs[e], 0, NROWS - 1);
  const u16* B = (e == NE) ? sw2b : ew2b + (size_t)e * DIM * K;
  int n0 = ny * 128;

  __shared__ u16 As[3 * 4096], Bs[3 * 4096];   // 48 KB

  int tid = threadIdx.x;
  int lane = tid & 63, wv = tid >> 6;
  int srow = tid >> 2, sg = tid & 3;
  int sk0 = (sg ^ ((srow >> 1) & 3)) * 8;
  int sk1 = (sg ^ (((srow + 64) >> 1) & 3)) * 8;
  int r0 = clampi(rowbase + min(m0 + srow, M - 1), 0, NROWS - 1);
  int r1 = clampi(rowbase + min(m0 + srow + 64, M - 1), 0, NROWS - 1);
  const u16* Ap0 = Gb + (size_t)r0 * K + sk0;
  const u16* Ap1 = Gb + (size_t)r1 * K + sk1;
  const u16* Bp0 = B + (size_t)(n0 + srow) * K + sk0;
  const u16* Bp1 = B + (size_t)(n0 + srow + 64) * K + sk1;
  int st0 = wv * 512, st1 = 2048 + wv * 512;

  int ln15 = lane & 15, qd = lane >> 4;
  int qsw = (qd ^ ((ln15 >> 1) & 3)) * 8;
  int wm = (wv >> 1) * 64, wn = (wv & 1) * 64;
  int aoff = (wm + ln15) * 32 + qsw;
  int boff = (wn + ln15) * 32 + qsw;

  f32x4 acc[4][4] = {};

  // prologue: stage tiles 0,1 (8 loads in flight)
#pragma unroll
  for (int b = 0; b < 2; ++b) {
    const int bb = b * 4096, kb = b * 32;
    GLL16(Ap0 + kb, As + bb + st0);   GLL16(Ap1 + kb, As + bb + st1);
    GLL16(Bp0 + kb, Bs + bb + st0);   GLL16(Bp1 + kb, Bs + bb + st1);
  }

#pragma unroll
  for (int t = 0; t < 14; ++t) {     // staging iterations (tiles 2..15)
    const int cur = (t % 3) * 4096;
    WAIT_VM_BARRIER(4);              // tile t landed; t+1 in flight; buf (t+2)%3 free
    const int nxt = ((t + 2) % 3) * 4096;
    const int kt = (t + 2) * 32;
    GLL16(Ap0 + kt, As + nxt + st0);   GLL16(Ap1 + kt, As + nxt + st1);
    GLL16(Bp0 + kt, Bs + nxt + st0);   GLL16(Bp1 + kt, Bs + nxt + st1);
    bf16x8 af[4], bf[4];
#pragma unroll
    for (int i = 0; i < 4; ++i) {
      af[i] = *reinterpret_cast<const bf16x8*>(&As[cur + aoff + i * 512]);
      bf[i] = *reinterpret_cast<const bf16x8*>(&Bs[cur + boff + i * 512]);
    }
    WAIT_LGKM0();
    __builtin_amdgcn_sched_barrier(0);
    __builtin_amdgcn_s_setprio(1);
#pragma unroll
    for (int i = 0; i < 4; ++i)
#pragma unroll
      for (int j = 0; j < 4; ++j)
        acc[i][j] = __builtin_amdgcn_mfma_f32_16x16x32_bf16(af[i], bf[j], acc[i][j], 0, 0, 0);
    __builtin_amdgcn_s_setprio(0);
  }
  // tail peels: t = 14 (vmcnt 4: tile 15 may still fly), t = 15 (vmcnt 0)
#pragma unroll
  for (int pt = 14; pt < 16; ++pt) {
    const int cur = (pt % 3) * 4096;
    if (pt == 14) { WAIT_VM_BARRIER(4); }
    else          { WAIT_VM_BARRIER(0); }
    bf16x8 af[4], bf[4];
#pragma unroll
    for (int i = 0; i < 4; ++i) {
      af[i] = *reinterpret_cast<const bf16x8*>(&As[cur + aoff + i * 512]);
      bf[i] = *reinterpret_cast<const bf16x8*>(&Bs[cur + boff + i * 512]);
    }
    WAIT_LGKM0();
    __builtin_amdgcn_sched_barrier(0);
    __builtin_amdgcn_s_setprio(1);
#pragma unroll
    for (int i = 0; i < 4; ++i)
#pragma unroll
      for (int j = 0; j < 4; ++j)
        acc[i][j] = __builtin_amdgcn_mfma_f32_16x16x32_bf16(af[i], bf[j], acc[i][j], 0, 0, 0);
    __builtin_amdgcn_s_setprio(0);
  }

  int mrem = M - m0;
#pragma unroll
  for (int i = 0; i < 4; ++i)
#pragma unroll
    for (int r2 = 0; r2 < 4; ++r2) {
      int ml = wm + i * 16 + qd * 4 + r2;
      if (ml < mrem) {
        int slot2 = clampi(rowbase + m0 + ml, 0, NROWS - 1);
        float cw = cwl[slot2];
#pragma unroll
        for (int j = 0; j < 4; ++j)
          O[(size_t)slot2 * DIM + n0 + wn + j * 16 + ln15] = f2bf(acc[i][j][r2] * cw);
      }
    }
}

// ---------------- combine: y[t] = sum of token's 3 slot rows ----------------
__global__ __launch_bounds__(256) void combine_kernel(
    const u16* __restrict__ O, const int* __restrict__ slotmap, float* __restrict__ y) {
  int t = blockIdx.x;
  int c = threadIdx.x;
  int s0 = clampi(slotmap[t * 3], 0, NROWS - 1);
  int s1 = clampi(slotmap[t * 3 + 1], 0, NROWS - 1);
  int s2 = clampi(slotmap[t * 3 + 2], 0, NROWS - 1);
  ushort4 a = reinterpret_cast<const ushort4*>(O + (size_t)s0 * DIM)[c];
  ushort4 b = reinterpret_cast<const ushort4*>(O + (size_t)s1 * DIM)[c];
  ushort4 d = reinterpret_cast<const ushort4*>(O + (size_t)s2 * DIM)[c];
  float4 r;
  r.x = bf2f(a.x) + bf2f(b.x) + bf2f(d.x);
  r.y = bf2f(a.y) + bf2f(b.y) + bf2f(d.y);
  r.z = bf2f(a.z) + bf2f(b.z) + bf2f(d.z);
  r.w = bf2f(a.w) + bf2f(b.w) + bf2f(d.w);
  reinterpret_cast<float4*>(y + (size_t)t * DIM)[c] = r;
}

// ---------------- launcher ----------------
extern "C" void kernel_launch(void* const* d_in, const int* in_sizes, int n_in,
                              void* d_out, int out_size, void* d_ws, size_t ws_size,
                              hipStream_t stream) {
  const float* x     = (const float*)d_in[0];
  const float* gw    = (const float*)d_in[1];
  const float* ebias = (const float*)d_in[2];
  const float* sw1   = (const float*)d_in[3];
  const float* sw2   = (const float*)d_in[4];
  const float* sw3   = (const float*)d_in[5];
  const float* ew1   = (const float*)d_in[6];
  const float* ew2   = (const float*)d_in[7];
  const float* ew3   = (const float*)d_in[8];
  float* y = (float*)d_out;
  float* probs = y + (size_t)T_TOK * DIM;

  char* ws = (char*)d_ws;
  size_t o = 0;
  auto alloc = [&](size_t bytes) -> char* {
    char* p = ws + o;
    o = (o + bytes + 255) & ~(size_t)255;
    return p;
  };
  u16* G    = (u16*)alloc((size_t)NROWS * FF * 2);
  u16* sw1b = (u16*)alloc((size_t)FF * DIM * 2);
  u16* sw2b = (u16*)alloc((size_t)FF * DIM * 2);
  u16* sw3b = (u16*)alloc((size_t)FF * DIM * 2);
  u16* ew2b = (u16*)alloc((size_t)NE * FF * DIM * 2);
  // aliased region: [xb | ew1b | ew3b] (live through silu) == O (live after silu)
  char* aliasBase = alloc((size_t)NROWS * DIM * 2);
  u16* xb   = (u16*)aliasBase;
  u16* ew1b = (u16*)(aliasBase + (size_t)T_TOK * DIM * 2);
  u16* ew3b = (u16*)(aliasBase + (size_t)T_TOK * DIM * 2 + (size_t)NE * FF * DIM * 2);
  u16* O    = (u16*)aliasBase;
  int*   topi    = (int*)alloc(T_TOK * 2 * 4);
  float* topw    = (float*)alloc(T_TOK * 2 * 4);
  int*   idx     = (int*)alloc(NROWS * 4);
  float* cwl     = (float*)alloc(NROWS * 4);
  int*   slotmap = (int*)alloc(T_TOK * 3 * 4);
  int2*  tab     = (int2*)alloc(MAXTILES * 8);
  int*   cnt_seg = (int*)alloc(NSEG * 16 * 4);
  int*   seg_base= (int*)alloc(NSEG * 16 * 4);
  int*   cnt     = (int*)alloc(256);
  int*   offs    = (int*)alloc(256);

  router_cvt_kernel<<<NSEG + TOTW4 / 256, 256, 0, stream>>>(
      x, gw, ebias, probs, topi, topw, cnt_seg, xb,
      sw1, sw2, sw3, ew1, ew2, ew3, sw1b, sw2b, sw3b, ew1b, ew2b, ew3b);
  scan_kernel<<<1, 256, 0, stream>>>(cnt_seg, cnt, offs, seg_base, tab);
  scatter_kernel<<<NSEG, 64, 0, stream>>>(topi, topw, seg_base, idx, cwl, slotmap);

  gemm_silu_kernel<<<1024, 256, 0, stream>>>(
      xb, sw1b, sw3b, ew1b, ew3b, G, tab, offs, cnt, idx);
  gemm_out_kernel<<<2048, 256, 0, stream>>>(
      G, sw2b, ew2b, O, tab, offs, cnt, cwl);
  combine_kernel<<<T_TOK, 256, 0, stream>>>(O, slotmap, y);
}

// Round 13
// 379.014 us; speedup vs baseline: 1.1882x; 1.1882x over previous
//
#include <hip/hip_runtime.h>

typedef unsigned short u16;
typedef __bf16 bf16_t;
typedef bf16_t bf16x8 __attribute__((ext_vector_type(8)));
typedef float f32x4 __attribute__((ext_vector_type(4)));

#define T_TOK 8192
#define DIM   1024
#define FF    512
#define NE    16
#define RBASE_SHARED (2 * T_TOK)     // shared group rowbase = 16384
#define NROWS (RBASE_SHARED + T_TOK) // 24576 total row-slots
#define MAXTILES 256
#define NSEG 512                     // 16 tokens per segment

__device__ __forceinline__ u16 f2bf(float f) {
  union { float f; unsigned u; } v; v.f = f;
  unsigned r = v.u + 0x7FFFu + ((v.u >> 16) & 1u);
  return (u16)(r >> 16);
}
__device__ __forceinline__ float bf2f(u16 h) {
  union { unsigned u; float f; } v; v.u = ((unsigned)h) << 16; return v.f;
}
__device__ __forceinline__ int clampi(int v, int lo, int hi) {
  return v < lo ? lo : (v > hi ? hi : v);
}

// async global->LDS, 16B per lane; LDS dest = wave-uniform base + lane*16
#define GLL16(g, l) __builtin_amdgcn_global_load_lds( \
    (const __attribute__((address_space(1))) void*)(g), \
    (__attribute__((address_space(3))) void*)(l), 16, 0, 0)

// fused waitcnt+barrier: single volatile asm with memory clobber = compile-time
// fence; no memory op can cross, and waitcnt/barrier are adjacent in the stream.
#define WAIT_VM_BARRIER(n) asm volatile("s_waitcnt vmcnt(" #n ")\n\ts_barrier" ::: "memory")
#define WAIT_LGKM0()       asm volatile("s_waitcnt lgkmcnt(0)" ::: "memory")
#define WAIT_LGKM4()       asm volatile("s_waitcnt lgkmcnt(4)" ::: "memory")

// ---------------- fused fp32 -> bf16 convert for the 6 weight inputs ----------------
// Separate kernel (NOT fused with router): round-11 fusion imposed the router's
// 188-VGPR allocation on 26k streaming blocks -> 11% occupancy -> 750 GB/s.
#define SW4  131072    // each shared weight: 512*1024/4
#define EW4  2097152   // each expert weight set: 16*512*1024/4
#define TOTW4 (3 * SW4 + 3 * EW4)   // 6684672; /256 = 26112 blocks

__global__ __launch_bounds__(256) void cvt_all_kernel(
    const float* __restrict__ sw1, const float* __restrict__ sw2,
    const float* __restrict__ sw3, const float* __restrict__ ew1,
    const float* __restrict__ ew2, const float* __restrict__ ew3,
    u16* __restrict__ sw1b, u16* __restrict__ sw2b, u16* __restrict__ sw3b,
    u16* __restrict__ ew1b, u16* __restrict__ ew2b, u16* __restrict__ ew3b) {
  int i = blockIdx.x * 256 + threadIdx.x;
  const float* s; u16* dst; int j;
  if (i < SW4)                      { s = sw1; dst = sw1b; j = i; }
  else if (i < 2 * SW4)             { s = sw2; dst = sw2b; j = i - SW4; }
  else if (i < 3 * SW4)             { s = sw3; dst = sw3b; j = i - 2 * SW4; }
  else if (i < 3 * SW4 + EW4)       { s = ew1; dst = ew1b; j = i - 3 * SW4; }
  else if (i < 3 * SW4 + 2 * EW4)   { s = ew2; dst = ew2b; j = i - (3 * SW4 + EW4); }
  else if (i < TOTW4)               { s = ew3; dst = ew3b; j = i - (3 * SW4 + 2 * EW4); }
  else return;
  float4 v = reinterpret_cast<const float4*>(s)[j];
  ushort4 o;
  o.x = f2bf(v.x); o.y = f2bf(v.y); o.z = f2bf(v.z); o.w = f2bf(v.w);
  reinterpret_cast<ushort4*>(dst)[j] = o;
}

// ---------------- router: fp32, coalesced, NO global atomics ----------------
// Router also emits xb (bf16 x) -- it already reads every element.
__global__ __launch_bounds__(256) void router_kernel(
    const float* __restrict__ x, const float* __restrict__ gw,
    const float* __restrict__ ebias, float* __restrict__ probs,
    int* __restrict__ topi, float* __restrict__ topw, int* __restrict__ cnt_seg,
    u16* __restrict__ xb) {
  __shared__ int hist[16];
  int tid = threadIdx.x;
  int lane = tid & 63, w = tid >> 6;
  if (tid < 16) hist[tid] = 0;
  __syncthreads();
  const float4* gv = reinterpret_cast<const float4*>(gw);
  for (int it = 0; it < 2; ++it) {
    int t0 = blockIdx.x * 16 + (w + 4 * it) * 2;
    const float4* x0 = reinterpret_cast<const float4*>(x + (size_t)t0 * DIM);
    const float4* x1 = reinterpret_cast<const float4*>(x + (size_t)(t0 + 1) * DIM);
    float4 xa[4], xc[4];
#pragma unroll
    for (int j = 0; j < 4; ++j) { xa[j] = x0[j * 64 + lane]; xc[j] = x1[j * 64 + lane]; }
    // emit bf16 x (coalesced 8B/lane stores)
    u16* xr0 = xb + (size_t)t0 * DIM;
    u16* xr1 = xb + (size_t)(t0 + 1) * DIM;
#pragma unroll
    for (int j = 0; j < 4; ++j) {
      ushort4 o0, o1;
      o0.x = f2bf(xa[j].x); o0.y = f2bf(xa[j].y); o0.z = f2bf(xa[j].z); o0.w = f2bf(xa[j].w);
      o1.x = f2bf(xc[j].x); o1.y = f2bf(xc[j].y); o1.z = f2bf(xc[j].z); o1.w = f2bf(xc[j].w);
      reinterpret_cast<ushort4*>(xr0)[j * 64 + lane] = o0;
      reinterpret_cast<ushort4*>(xr1)[j * 64 + lane] = o1;
    }
    float p0[16], p1[16];
#pragma unroll
    for (int e = 0; e < NE; ++e) {
      float s0 = 0.f, s1 = 0.f;
#pragma unroll
      for (int j = 0; j < 4; ++j) {
        float4 g = gv[e * 256 + j * 64 + lane];
        s0 += xa[j].x * g.x + xa[j].y * g.y + xa[j].z * g.z + xa[j].w * g.w;
        s1 += xc[j].x * g.x + xc[j].y * g.y + xc[j].z * g.z + xc[j].w * g.w;
      }
#pragma unroll
      for (int d = 1; d < 64; d <<= 1) { s0 += __shfl_xor(s0, d); s1 += __shfl_xor(s1, d); }
      float b = ebias[e];
      p0[e] = s0 + b; p1[e] = s1 + b;
    }
    float m0 = p0[0], m1 = p1[0];
#pragma unroll
    for (int e = 1; e < NE; ++e) { m0 = fmaxf(m0, p0[e]); m1 = fmaxf(m1, p1[e]); }
    float sum0 = 0.f, sum1 = 0.f;
#pragma unroll
    for (int e = 0; e < NE; ++e) {
      p0[e] = __expf(p0[e] - m0); sum0 += p0[e];
      p1[e] = __expf(p1[e] - m1); sum1 += p1[e];
    }
    float inv0 = 1.f / sum0, inv1 = 1.f / sum1;
#pragma unroll
    for (int e = 0; e < NE; ++e) { p0[e] *= inv0; p1[e] *= inv1; }
    if (lane == 0) {
#pragma unroll
      for (int j = 0; j < 4; ++j)
        reinterpret_cast<float4*>(probs + (size_t)t0 * NE)[j] =
            make_float4(p0[4 * j], p0[4 * j + 1], p0[4 * j + 2], p0[4 * j + 3]);
      float b1 = -1.f, b2 = -1.f; int i1 = 0, i2 = 0;
#pragma unroll
      for (int e = 0; e < NE; ++e) {
        float pe = p0[e];
        if (pe > b1) { b2 = b1; i2 = i1; b1 = pe; i1 = e; }
        else if (pe > b2) { b2 = pe; i2 = e; }
      }
      float ws = b1 + b2;
      reinterpret_cast<int2*>(topi)[t0] = make_int2(i1, i2);
      reinterpret_cast<float2*>(topw)[t0] = make_float2(b1 / ws, b2 / ws);
      atomicAdd(&hist[i1], 1); atomicAdd(&hist[i2], 1);
    }
    if (lane == 1) {
      int t1 = t0 + 1;
#pragma unroll
      for (int j = 0; j < 4; ++j)
        reinterpret_cast<float4*>(probs + (size_t)t1 * NE)[j] =
            make_float4(p1[4 * j], p1[4 * j + 1], p1[4 * j + 2], p1[4 * j + 3]);
      float b1 = -1.f, b2 = -1.f; int i1 = 0, i2 = 0;
#pragma unroll
      for (int e = 0; e < NE; ++e) {
        float pe = p1[e];
        if (pe > b1) { b2 = b1; i2 = i1; b1 = pe; i1 = e; }
        else if (pe > b2) { b2 = pe; i2 = e; }
      }
      float ws = b1 + b2;
      reinterpret_cast<int2*>(topi)[t1] = make_int2(i1, i2);
      reinterpret_cast<float2*>(topw)[t1] = make_float2(b1 / ws, b2 / ws);
      atomicAdd(&hist[i1], 1); atomicAdd(&hist[i2], 1);
    }
  }
  __syncthreads();
  if (tid < 16) cnt_seg[blockIdx.x * 16 + tid] = hist[tid];
}

// ---------------- scan: parallel prefix over segments, tile table ----------------
// tab is XCD-CHUNKED: tab[c*32+slot] = tiles for XCD chunk c. Routed experts
// assigned whole to least-loaded chunk; shared tiles round-robin 8/chunk.
__global__ __launch_bounds__(256) void scan_kernel(
    const int* __restrict__ cnt_seg, int* __restrict__ cnt, int* __restrict__ offs,
    int* __restrict__ seg_base, int2* __restrict__ tab) {
  __shared__ int chunk_sum[16][16];   // [chunk][e], chunk = 32 segs
  __shared__ int chunk_base[16][16];
  __shared__ int tot[16], off_s[17];
  int tid = threadIdx.x;
  int e = tid & 15, c = tid >> 4;
  int s0 = 0;
  for (int s = 0; s < 32; ++s) s0 += cnt_seg[(c * 32 + s) * 16 + e];
  chunk_sum[c][e] = s0;
  __syncthreads();
  if (tid < 16) {
    int r = 0;
    for (int c2 = 0; c2 < 16; ++c2) { chunk_base[c2][tid] = r; r += chunk_sum[c2][tid]; }
    tot[tid] = r;
  }
  __syncthreads();
  if (tid == 0) {
    int a = 0;
    for (int i = 0; i < 16; ++i) { off_s[i] = a; offs[i] = a; cnt[i] = tot[i]; a += tot[i]; }
    off_s[16] = RBASE_SHARED; offs[16] = RBASE_SHARED;
    for (int i = 0; i < MAXTILES; ++i) tab[i] = make_int2(-1, 0);
    int loadc[8]  = {0, 0, 0, 0, 0, 0, 0, 0};
    int cursor[8] = {0, 0, 0, 0, 0, 0, 0, 0};
    for (int g = 0; g < 16; ++g) {                // routed experts
      int nt = (tot[g] + 127) >> 7;
      if (nt == 0) continue;
      int best = 0;
      for (int c2 = 1; c2 < 8; ++c2) if (loadc[c2] < loadc[best]) best = c2;
      loadc[best] += nt;
      int c2 = best;
      for (int ti = 0; ti < nt; ++ti) {
        while (cursor[c2] >= 32) c2 = (c2 + 1) & 7;   // spill (rare), keeps all tiles
        tab[c2 * 32 + cursor[c2]] = make_int2(g, ti * 128);
        cursor[c2]++;
      }
    }
    for (int ti = 0; ti < 64; ++ti) {             // shared: 8 tiles per chunk
      int c2 = ti & 7;
      while (cursor[c2] >= 32) c2 = (c2 + 1) & 7;
      tab[c2 * 32 + cursor[c2]] = make_int2(16, ti * 128);
      cursor[c2]++;
    }
  }
  __syncthreads();
  int r = off_s[e] + chunk_base[c][e];
  for (int s = 0; s < 32; ++s) {
    int seg = c * 32 + s;
    seg_base[seg * 16 + e] = r;
    r += cnt_seg[seg * 16 + e];
  }
}

// ---------------- scatter: deterministic ranks, NO atomics ----------------
__global__ __launch_bounds__(64) void scatter_kernel(
    const int* __restrict__ topi, const float* __restrict__ topw,
    const int* __restrict__ seg_base,
    int* __restrict__ idx, float* __restrict__ cwl, int* __restrict__ slotmap) {
  __shared__ int ti[16][2]; __shared__ float tw[16][2]; __shared__ int base[16];
  int b = blockIdx.x;            // 512 segments
  int tid = threadIdx.x;         // 64
  if (tid < 16) {
    int t = b * 16 + tid;
    int2 pp = reinterpret_cast<const int2*>(topi)[t];
    ti[tid][0] = clampi(pp.x, 0, 15); ti[tid][1] = clampi(pp.y, 0, 15);
    float2 ww = reinterpret_cast<const float2*>(topw)[t];
    tw[tid][0] = ww.x; tw[tid][1] = ww.y;
    base[tid] = seg_base[b * 16 + tid];
  }
  __syncthreads();
  if (tid < 32) {
    int l = tid >> 1, s = tid & 1;
    int t = b * 16 + l;
    int e = ti[l][s];
    int rank = 0;
    for (int t2 = 0; t2 < 16; ++t2) {
      if (ti[t2][0] == e && (t2 < l || (t2 == l && 0 < s))) ++rank;
      if (ti[t2][1] == e && (t2 < l)) ++rank;
    }
    int slot = clampi(base[e] + rank, 0, NROWS - 1);
    idx[slot] = t; cwl[slot] = tw[l][s]; slotmap[t * 3 + s] = slot;
  } else if (tid < 48) {
    int l = tid - 32;
    int t = b * 16 + l;
    int sh = RBASE_SHARED + t;
    idx[sh] = t; cwl[sh] = 1.0f; slotmap[t * 3 + 2] = sh;
  }
}

// ---------------- grouped GEMM1: G = silu(A@W1^T) * (A@W3^T), bf16 ----------------
// Round-9 structure + B3-read overlap. Issue order is PINNED with a
// sched_barrier(0) between the af/b1f group and the b3f group so that
// lgkmcnt(4) (in-order DS retire) provably certifies af+b1f landed while
// b3f is still in flight; acc1 MFMAs hide b3f's LDS latency.
__global__ __launch_bounds__(256, 2) void gemm_silu_kernel(
    const u16* __restrict__ A, const u16* __restrict__ sw1b, const u16* __restrict__ sw3b,
    const u16* __restrict__ ew1b, const u16* __restrict__ ew3b, u16* __restrict__ G,
    const int2* __restrict__ tab, const int* __restrict__ offs,
    const int* __restrict__ cnt, const int* __restrict__ gidx) {
  const int K = DIM;
  int orig = blockIdx.x;                  // 1024 blocks, 1-D grid
  int xcd = orig & 7;
  int u = orig >> 3;                      // [0,128)
  int tslot = u >> 2, ny = u & 3;         // ny fastest -> CU = (4*tslot+ny)%32
  int tileid = xcd * 32 + tslot;
  int2 te = tab[tileid];
  int e = te.x;
  if (e < 0) return;                      // block-uniform exit (before barriers)
  e = clampi(e, 0, NE);
  int m0 = te.y;
  int M = (e == NE) ? T_TOK : cnt[e];
  M = clampi(M, 1, T_TOK);
  int rowbase = clampi(offs[e], 0, NROWS - 1);
  const u16* B1 = (e == NE) ? sw1b : ew1b + (size_t)e * FF * K;
  const u16* B3 = (e == NE) ? sw3b : ew3b + (size_t)e * FF * K;
  int n0 = ny * 128;

  __shared__ u16 As[3 * 4096], B1s[3 * 4096], B3s[3 * 4096];   // 72 KB

  int tid = threadIdx.x;
  int lane = tid & 63, wv = tid >> 6;
  int srow = tid >> 2, sg = tid & 3;
  int sk0 = (sg ^ ((srow >> 1) & 3)) * 8;
  int sk1 = (sg ^ (((srow + 64) >> 1) & 3)) * 8;
  int r0 = min(m0 + srow, M - 1);
  int r1 = min(m0 + srow + 64, M - 1);
  int ga0 = clampi(gidx[clampi(rowbase + r0, 0, NROWS - 1)], 0, T_TOK - 1);
  int ga1 = clampi(gidx[clampi(rowbase + r1, 0, NROWS - 1)], 0, T_TOK - 1);
  const u16* Ap0 = A + (size_t)ga0 * K + sk0;
  const u16* Ap1 = A + (size_t)ga1 * K + sk1;
  const u16* B1p0 = B1 + (size_t)(n0 + srow) * K + sk0;
  const u16* B1p1 = B1 + (size_t)(n0 + srow + 64) * K + sk1;
  const u16* B3p0 = B3 + (size_t)(n0 + srow) * K + sk0;
  const u16* B3p1 = B3 + (size_t)(n0 + srow + 64) * K + sk1;
  int st0 = wv * 512, st1 = 2048 + wv * 512;   // per-wave staging dests (u16 units)

  int ln15 = lane & 15, qd = lane >> 4;
  int qsw = (qd ^ ((ln15 >> 1) & 3)) * 8;
  int wm = (wv >> 1) * 64, wn = (wv & 1) * 64;
  int aoff = (wm + ln15) * 32 + qsw;
  int boff = (wn + ln15) * 32 + qsw;

  f32x4 acc1[4][4] = {};
  f32x4 acc3[4][4] = {};

  // prologue: stage tiles 0,1 (12 loads in flight)
#pragma unroll
  for (int b = 0; b < 2; ++b) {
    const int bb = b * 4096, kb = b * 32;
    GLL16(Ap0 + kb, As + bb + st0);      GLL16(Ap1 + kb, As + bb + st1);
    GLL16(B1p0 + kb, B1s + bb + st0);    GLL16(B1p1 + kb, B1s + bb + st1);
    GLL16(B3p0 + kb, B3s + bb + st0);    GLL16(B3p1 + kb, B3s + bb + st1);
  }

#pragma unroll
  for (int t = 0; t < 30; ++t) {     // staging iterations, fully unrolled
    const int cur = (t % 3) * 4096;
    WAIT_VM_BARRIER(6);              // tile t landed; t+1 in flight; buf (t+2)%3 free
    const int nxt = ((t + 2) % 3) * 4096;
    const int kt = (t + 2) * 32;     // stage tile t+2 (earliest issue, imm offsets)
    GLL16(Ap0 + kt, As + nxt + st0);     GLL16(Ap1 + kt, As + nxt + st1);
    GLL16(B1p0 + kt, B1s + nxt + st0);   GLL16(B1p1 + kt, B1s + nxt + st1);
    GLL16(B3p0 + kt, B3s + nxt + st0);   GLL16(B3p1 + kt, B3s + nxt + st1);
    bf16x8 af[4], b1f[4], b3f[4];
#pragma unroll
    for (int i = 0; i < 4; ++i) {
      af[i]  = *reinterpret_cast<const bf16x8*>(&As[cur + aoff + i * 512]);
      b1f[i] = *reinterpret_cast<const bf16x8*>(&B1s[cur + boff + i * 512]);
    }
    __builtin_amdgcn_sched_barrier(0);   // PIN: af+b1f reads issue before b3f reads
#pragma unroll
    for (int i = 0; i < 4; ++i)
      b3f[i] = *reinterpret_cast<const bf16x8*>(&B3s[cur + boff + i * 512]);
    WAIT_LGKM4();                    // af+b1f landed (in-order DS); b3f in flight
    __builtin_amdgcn_sched_barrier(0);
    __builtin_amdgcn_s_setprio(1);
#pragma unroll
    for (int i = 0; i < 4; ++i)
#pragma unroll
      for (int j = 0; j < 4; ++j)
        acc1[i][j] = __builtin_amdgcn_mfma_f32_16x16x32_bf16(af[i], b1f[j], acc1[i][j], 0, 0, 0);
    __builtin_amdgcn_s_setprio(0);
    WAIT_LGKM0();                    // b3f landed (latency hidden under acc1 cluster)
    __builtin_amdgcn_sched_barrier(0);
    __builtin_amdgcn_s_setprio(1);
#pragma unroll
    for (int i = 0; i < 4; ++i)
#pragma unroll
      for (int j = 0; j < 4; ++j)
        acc3[i][j] = __builtin_amdgcn_mfma_f32_16x16x32_bf16(af[i], b3f[j], acc3[i][j], 0, 0, 0);
    __builtin_amdgcn_s_setprio(0);
  }
  // tail peels: t = 30 (vmcnt 6: tile 31 may still fly), t = 31 (vmcnt 0)
#pragma unroll
  for (int pt = 30; pt < 32; ++pt) {
    const int cur = (pt % 3) * 4096;
    if (pt == 30) { WAIT_VM_BARRIER(6); }
    else          { WAIT_VM_BARRIER(0); }
    bf16x8 af[4], b1f[4], b3f[4];
#pragma unroll
    for (int i = 0; i < 4; ++i) {
      af[i]  = *reinterpret_cast<const bf16x8*>(&As[cur + aoff + i * 512]);
      b1f[i] = *reinterpret_cast<const bf16x8*>(&B1s[cur + boff + i * 512]);
    }
    __builtin_amdgcn_sched_barrier(0);   // PIN read order
#pragma unroll
    for (int i = 0; i < 4; ++i)
      b3f[i] = *reinterpret_cast<const bf16x8*>(&B3s[cur + boff + i * 512]);
    WAIT_LGKM4();
    __builtin_amdgcn_sched_barrier(0);
    __builtin_amdgcn_s_setprio(1);
#pragma unroll
    for (int i = 0; i < 4; ++i)
#pragma unroll
      for (int j = 0; j < 4; ++j)
        acc1[i][j] = __builtin_amdgcn_mfma_f32_16x16x32_bf16(af[i], b1f[j], acc1[i][j], 0, 0, 0);
    __builtin_amdgcn_s_setprio(0);
    WAIT_LGKM0();
    __builtin_amdgcn_sched_barrier(0);
    __builtin_amdgcn_s_setprio(1);
#pragma unroll
    for (int i = 0; i < 4; ++i)
#pragma unroll
      for (int j = 0; j < 4; ++j)
        acc3[i][j] = __builtin_amdgcn_mfma_f32_16x16x32_bf16(af[i], b3f[j], acc3[i][j], 0, 0, 0);
    __builtin_amdgcn_s_setprio(0);
  }

  int mrem = M - m0;
#pragma unroll
  for (int i = 0; i < 4; ++i)
#pragma unroll
    for (int r2 = 0; r2 < 4; ++r2) {
      int ml = wm + i * 16 + qd * 4 + r2;
      if (ml < mrem) {
        size_t orow = (size_t)clampi(rowbase + m0 + ml, 0, NROWS - 1);
#pragma unroll
        for (int j = 0; j < 4; ++j) {
          float z1 = acc1[i][j][r2], z3 = acc3[i][j][r2];
          float g = z1 / (1.f + __expf(-z1)) * z3;
          G[orow * FF + n0 + wn + j * 16 + ln15] = f2bf(g);
        }
      }
    }
}

// ---------------- grouped GEMM2: O[slot] = cw * (G @ W2^T), bf16 ----------------
// Round-9 structure: 2048 blocks, ny-fastest decode, depth-2, single barrier.
__global__ __launch_bounds__(256, 2) void gemm_out_kernel(
    const u16* __restrict__ Gb, const u16* __restrict__ sw2b, const u16* __restrict__ ew2b,
    u16* __restrict__ O, const int2* __restrict__ tab, const int* __restrict__ offs,
    const int* __restrict__ cnt, const float* __restrict__ cwl) {
  const int K = FF;
  int orig = blockIdx.x;                  // 2048 blocks, 1-D grid
  int xcd = orig & 7;
  int u = orig >> 3;                      // [0,256)
  int tslot = u >> 3, ny = u & 7;         // ny fastest -> CU = (8*tslot+ny)%32
  int tileid = xcd * 32 + tslot;
  int2 te = tab[tileid];
  int e = te.x;
  if (e < 0) return;
  e = clampi(e, 0, NE);
  int m0 = te.y;
  int M = (e == NE) ? T_TOK : cnt[e];
  M = clampi(M, 1, T_TOK);
  int rowbase = clampi(offs[e], 0, NROWS - 1);
  const u16* B = (e == NE) ? sw2b : ew2b + (size_t)e * DIM * K;
  int n0 = ny * 128;

  __shared__ u16 As[3 * 4096], Bs[3 * 4096];   // 48 KB

  int tid = threadIdx.x;
  int lane = tid & 63, wv = tid >> 6;
  int srow = tid >> 2, sg = tid & 3;
  int sk0 = (sg ^ ((srow >> 1) & 3)) * 8;
  int sk1 = (sg ^ (((srow + 64) >> 1) & 3)) * 8;
  int r0 = clampi(rowbase + min(m0 + srow, M - 1), 0, NROWS - 1);
  int r1 = clampi(rowbase + min(m0 + srow + 64, M - 1), 0, NROWS - 1);
  const u16* Ap0 = Gb + (size_t)r0 * K + sk0;
  const u16* Ap1 = Gb + (size_t)r1 * K + sk1;
  const u16* Bp0 = B + (size_t)(n0 + srow) * K + sk0;
  const u16* Bp1 = B + (size_t)(n0 + srow + 64) * K + sk1;
  int st0 = wv * 512, st1 = 2048 + wv * 512;

  int ln15 = lane & 15, qd = lane >> 4;
  int qsw = (qd ^ ((ln15 >> 1) & 3)) * 8;
  int wm = (wv >> 1) * 64, wn = (wv & 1) * 64;
  int aoff = (wm + ln15) * 32 + qsw;
  int boff = (wn + ln15) * 32 + qsw;

  f32x4 acc[4][4] = {};

  // prologue: stage tiles 0,1 (8 loads in flight)
#pragma unroll
  for (int b = 0; b < 2; ++b) {
    const int bb = b * 4096, kb = b * 32;
    GLL16(Ap0 + kb, As + bb + st0);   GLL16(Ap1 + kb, As + bb + st1);
    GLL16(Bp0 + kb, Bs + bb + st0);   GLL16(Bp1 + kb, Bs + bb + st1);
  }

#pragma unroll
  for (int t = 0; t < 14; ++t) {     // staging iterations (tiles 2..15)
    const int cur = (t % 3) * 4096;
    WAIT_VM_BARRIER(4);              // tile t landed; t+1 in flight; buf (t+2)%3 free
    const int nxt = ((t + 2) % 3) * 4096;
    const int kt = (t + 2) * 32;
    GLL16(Ap0 + kt, As + nxt + st0);   GLL16(Ap1 + kt, As + nxt + st1);
    GLL16(Bp0 + kt, Bs + nxt + st0);   GLL16(Bp1 + kt, Bs + nxt + st1);
    bf16x8 af[4], bf[4];
#pragma unroll
    for (int i = 0; i < 4; ++i) {
      af[i] = *reinterpret_cast<const bf16x8*>(&As[cur + aoff + i * 512]);
      bf[i] = *reinterpret_cast<const bf16x8*>(&Bs[cur + boff + i * 512]);
    }
    WAIT_LGKM0();
    __builtin_amdgcn_sched_barrier(0);
    __builtin_amdgcn_s_setprio(1);
#pragma unroll
    for (int i = 0; i < 4; ++i)
#pragma unroll
      for (int j = 0; j < 4; ++j)
        acc[i][j] = __builtin_amdgcn_mfma_f32_16x16x32_bf16(af[i], bf[j], acc[i][j], 0, 0, 0);
    __builtin_amdgcn_s_setprio(0);
  }
  // tail peels: t = 14 (vmcnt 4: tile 15 may still fly), t = 15 (vmcnt 0)
#pragma unroll
  for (int pt = 14; pt < 16; ++pt) {
    const int cur = (pt % 3) * 4096;
    if (pt == 14) { WAIT_VM_BARRIER(4); }
    else          { WAIT_VM_BARRIER(0); }
    bf16x8 af[4], bf[4];
#pragma unroll
    for (int i = 0; i < 4; ++i) {
      af[i] = *reinterpret_cast<const bf16x8*>(&As[cur + aoff + i * 512]);
      bf[i] = *reinterpret_cast<const bf16x8*>(&Bs[cur + boff + i * 512]);
    }
    WAIT_LGKM0();
    __builtin_amdgcn_sched_barrier(0);
    __builtin_amdgcn_s_setprio(1);
#pragma unroll
    for (int i = 0; i < 4; ++i)
#pragma unroll
      for (int j = 0; j < 4; ++j)
        acc[i][j] = __builtin_amdgcn_mfma_f32_16x16x32_bf16(af[i], bf[j], acc[i][j], 0, 0, 0);
    __builtin_amdgcn_s_setprio(0);
  }

  int mrem = M - m0;
#pragma unroll
  for (int i = 0; i < 4; ++i)
#pragma unroll
    for (int r2 = 0; r2 < 4; ++r2) {
      int ml = wm + i * 16 + qd * 4 + r2;
      if (ml < mrem) {
        int slot2 = clampi(rowbase + m0 + ml, 0, NROWS - 1);
        float cw = cwl[slot2];
#pragma unroll
        for (int j = 0; j < 4; ++j)
          O[(size_t)slot2 * DIM + n0 + wn + j * 16 + ln15] = f2bf(acc[i][j][r2] * cw);
      }
    }
}

// ---------------- combine: y[t] = sum of token's 3 slot rows ----------------
__global__ __launch_bounds__(256) void combine_kernel(
    const u16* __restrict__ O, const int* __restrict__ slotmap, float* __restrict__ y) {
  int t = blockIdx.x;
  int c = threadIdx.x;
  int s0 = clampi(slotmap[t * 3], 0, NROWS - 1);
  int s1 = clampi(slotmap[t * 3 + 1], 0, NROWS - 1);
  int s2 = clampi(slotmap[t * 3 + 2], 0, NROWS - 1);
  ushort4 a = reinterpret_cast<const ushort4*>(O + (size_t)s0 * DIM)[c];
  ushort4 b = reinterpret_cast<const ushort4*>(O + (size_t)s1 * DIM)[c];
  ushort4 d = reinterpret_cast<const ushort4*>(O + (size_t)s2 * DIM)[c];
  float4 r;
  r.x = bf2f(a.x) + bf2f(b.x) + bf2f(d.x);
  r.y = bf2f(a.y) + bf2f(b.y) + bf2f(d.y);
  r.z = bf2f(a.z) + bf2f(b.z) + bf2f(d.z);
  r.w = bf2f(a.w) + bf2f(b.w) + bf2f(d.w);
  reinterpret_cast<float4*>(y + (size_t)t * DIM)[c] = r;
}

// ---------------- launcher ----------------
extern "C" void kernel_launch(void* const* d_in, const int* in_sizes, int n_in,
                              void* d_out, int out_size, void* d_ws, size_t ws_size,
                              hipStream_t stream) {
  const float* x     = (const float*)d_in[0];
  const float* gw    = (const float*)d_in[1];
  const float* ebias = (const float*)d_in[2];
  const float* sw1   = (const float*)d_in[3];
  const float* sw2   = (const float*)d_in[4];
  const float* sw3   = (const float*)d_in[5];
  const float* ew1   = (const float*)d_in[6];
  const float* ew2   = (const float*)d_in[7];
  const float* ew3   = (const float*)d_in[8];
  float* y = (float*)d_out;
  float* probs = y + (size_t)T_TOK * DIM;

  char* ws = (char*)d_ws;
  size_t o = 0;
  auto alloc = [&](size_t bytes) -> char* {
    char* p = ws + o;
    o = (o + bytes + 255) & ~(size_t)255;
    return p;
  };
  u16* G    = (u16*)alloc((size_t)NROWS * FF * 2);
  u16* sw1b = (u16*)alloc((size_t)FF * DIM * 2);
  u16* sw2b = (u16*)alloc((size_t)FF * DIM * 2);
  u16* sw3b = (u16*)alloc((size_t)FF * DIM * 2);
  u16* ew2b = (u16*)alloc((size_t)NE * FF * DIM * 2);
  // aliased region: [xb | ew1b | ew3b] (live through silu) == O (live after silu)
  char* aliasBase = alloc((size_t)NROWS * DIM * 2);
  u16* xb   = (u16*)aliasBase;
  u16* ew1b = (u16*)(aliasBase + (size_t)T_TOK * DIM * 2);
  u16* ew3b = (u16*)(aliasBase + (size_t)T_TOK * DIM * 2 + (size_t)NE * FF * DIM * 2);
  u16* O    = (u16*)aliasBase;
  int*   topi    = (int*)alloc(T_TOK * 2 * 4);
  float* topw    = (float*)alloc(T_TOK * 2 * 4);
  int*   idx     = (int*)alloc(NROWS * 4);
  float* cwl     = (float*)alloc(NROWS * 4);
  int*   slotmap = (int*)alloc(T_TOK * 3 * 4);
  int2*  tab     = (int2*)alloc(MAXTILES * 8);
  int*   cnt_seg = (int*)alloc(NSEG * 16 * 4);
  int*   seg_base= (int*)alloc(NSEG * 16 * 4);
  int*   cnt     = (int*)alloc(256);
  int*   offs    = (int*)alloc(256);

  router_kernel<<<NSEG, 256, 0, stream>>>(x, gw, ebias, probs, topi, topw, cnt_seg, xb);
  scan_kernel<<<1, 256, 0, stream>>>(cnt_seg, cnt, offs, seg_base, tab);
  scatter_kernel<<<NSEG, 64, 0, stream>>>(topi, topw, seg_base, idx, cwl, slotmap);
  cvt_all_kernel<<<TOTW4 / 256, 256, 0, stream>>>(sw1, sw2, sw3, ew1, ew2, ew3,
                                                  sw1b, sw2b, sw3b, ew1b, ew2b, ew3b);

  gemm_silu_kernel<<<1024, 256, 0, stream>>>(
      xb, sw1b, sw3b, ew1b, ew3b, G, tab, offs, cnt, idx);
  gemm_out_kernel<<<2048, 256, 0, stream>>>(
      G, sw2b, ew2b, O, tab, offs, cnt, cwl);
  combine_kernel<<<T_TOK, 256, 0, stream>>>(O, slotmap, y);
}